// Round 4
// baseline (1102.206 us; speedup 1.0000x reference)
//
#include <hip/hip_runtime.h>
#include <math.h>

typedef __attribute__((ext_vector_type(8))) short bf16x8;   // 8 bf16 in 4 VGPRs
typedef __attribute__((ext_vector_type(4))) float f32x4;
typedef unsigned short u16;

__device__ __forceinline__ u16 f2bf(float f) {
  unsigned u = __float_as_uint(f);
  return (u16)((u + 0x7FFFu + ((u >> 16) & 1u)) >> 16);   // RNE
}
__device__ __forceinline__ float bf2f(u16 h) {
  return __uint_as_float(((unsigned)h) << 16);
}

__device__ __forceinline__ void gload16(const u16* g, void* lds) {
  __builtin_amdgcn_global_load_lds(
      (const __attribute__((address_space(1))) unsigned int*)g,
      (__attribute__((address_space(3))) unsigned int*)lds, 16, 0, 0);
}

// ---------------------------------------------------------------------------
// MFMA core (proven in R2): 128x128 tile, BK=32, 256 threads (4 waves = 2x2
// quadrants of 4x4 16x16x32 fragments). K mult of 32; padded buffers.
// ---------------------------------------------------------------------------
__device__ __forceinline__ void mfma_core(
    const u16* __restrict__ A, int lda,
    const u16* __restrict__ B, int ldb,
    int K, f32x4 (&acc)[4][4], u16* As, u16* Bs)
{
  const int tid = threadIdx.x;
  const int l = tid & 63, w = tid >> 6;
  const int srow = w * 16 + (l >> 2);
  const int kel  = (l & 3) * 8;
  char* AsB = (char*)As + w * 1024;
  char* BsB = (char*)Bs + w * 1024;
  const u16* Ap  = A + (size_t)srow * lda + kel;
  const u16* Ap2 = A + (size_t)(srow + 64) * lda + kel;
  const u16* Bp  = B + (size_t)srow * ldb + kel;
  const u16* Bp2 = B + (size_t)(srow + 64) * ldb + kel;
  const int wm = w >> 1, wn = w & 1;
  const int aoff = (wm * 64 + (l & 15)) * 32 + (l >> 4) * 8;
  const int boff = (wn * 64 + (l & 15)) * 32 + (l >> 4) * 8;
  for (int kb = 0; kb < K; kb += 32) {
    __syncthreads();
    gload16(Ap + kb,  AsB);
    gload16(Ap2 + kb, AsB + 4096);
    gload16(Bp + kb,  BsB);
    gload16(Bp2 + kb, BsB + 4096);
    __syncthreads();
    bf16x8 av[4], bv[4];
#pragma unroll
    for (int i = 0; i < 4; ++i) {
      av[i] = *(const bf16x8*)(As + aoff + i * 16 * 32);
      bv[i] = *(const bf16x8*)(Bs + boff + i * 16 * 32);
    }
#pragma unroll
    for (int i = 0; i < 4; ++i)
#pragma unroll
      for (int j = 0; j < 4; ++j)
        acc[i][j] = __builtin_amdgcn_mfma_f32_16x16x32_bf16(av[i], bv[j], acc[i][j], 0, 0, 0);
  }
}

// ---------------------------------------------------------------------------
// f32 -> bf16 pad-copy
// ---------------------------------------------------------------------------
__global__ __launch_bounds__(256) void k_padcvt(
    const float* __restrict__ src, u16* __restrict__ dst,
    int srcR, int dstR, int C, long long dstStride, long long dstOff, long long total)
{
  long long idx = (long long)blockIdx.x * 256 + threadIdx.x;
  if (idx >= total) return;
  long long per = (long long)dstR * C;
  int g  = (int)(idx / per);
  int r2 = (int)(idx % per);
  int rr = r2 / C, c = r2 - rr * C;
  float v = (rr < srcR) ? src[((long long)g * srcR + rr) * C + c] : 0.f;
  dst[g * dstStride + dstOff + (long long)rr * C + c] = f2bf(v);
}

// Kt[h][o(1024)][NB] = Wk[h] x embA^T
__global__ __launch_bounds__(256) void k_kt(const u16* __restrict__ embA,
    const u16* __restrict__ WkB, u16* __restrict__ Kt, int b0, int NB)
{
  __shared__ u16 As[128 * 32], Bs[128 * 32];
  const int h = blockIdx.z;
  const int m0 = blockIdx.y * 128, n0 = blockIdx.x * 128;
  const u16* A = WkB + (size_t)h * 1024 * 960 + (size_t)m0 * 960;
  const u16* B = embA + (size_t)(b0 * 224 + n0) * 960;
  f32x4 acc[4][4] = {};
  mfma_core(A, 960, B, 960, 960, acc, As, Bs);
  const int tid = threadIdx.x, l = tid & 63, w = tid >> 6, wm = w >> 1, wn = w & 1;
  u16* C = Kt + (size_t)h * 1024 * NB;
#pragma unroll
  for (int i = 0; i < 4; ++i) {
    const int gm0 = m0 + wm * 64 + i * 16 + (l >> 4) * 4;
#pragma unroll
    for (int j = 0; j < 4; ++j) {
      const int n = n0 + wn * 64 + j * 16 + (l & 15);
#pragma unroll
      for (int r = 0; r < 4; ++r)
        C[(size_t)(gm0 + r) * NB + n] = f2bf(acc[i][j][r]);
    }
  }
}

// V[lb][h][n(256 pad)][o(1024)] = embA x Wv[h]^T
__global__ __launch_bounds__(256) void k_v(const u16* __restrict__ embA,
    const u16* __restrict__ WvB, u16* __restrict__ V, int b0, int NB)
{
  __shared__ u16 As[128 * 32], Bs[128 * 32];
  const int h = blockIdx.z;
  const int m0 = blockIdx.y * 128, n0 = blockIdx.x * 128;
  const u16* A = embA + (size_t)(b0 * 224 + m0) * 960;
  const u16* B = WvB + (size_t)h * 1024 * 960 + (size_t)n0 * 960;
  f32x4 acc[4][4] = {};
  mfma_core(A, 960, B, 960, 960, acc, As, Bs);
  const int tid = threadIdx.x, l = tid & 63, w = tid >> 6, wm = w >> 1, wn = w & 1;
#pragma unroll
  for (int i = 0; i < 4; ++i) {
    const int t0 = m0 + wm * 64 + i * 16 + (l >> 4) * 4;
#pragma unroll
    for (int r = 0; r < 4; ++r) {
      const int t = t0 + r;
      const int lb = t / 224, n = t - lb * 224;
      u16* C = V + ((size_t)(lb * 4 + h) * 256 + n) * 1024;
#pragma unroll
      for (int j = 0; j < 4; ++j) {
        const int col = n0 + wn * 64 + j * 16 + (l & 15);
        C[col] = f2bf(acc[i][j][r]);
      }
    }
  }
}

// Qt[h][ccat(1024)][NB] = Wq_br[h] x emb_br^T  (branch slices read from embA)
__global__ __launch_bounds__(256) void k_q(const u16* __restrict__ embA,
    const u16* __restrict__ WqB, u16* __restrict__ Qt, int b0, int NB)
{
  __shared__ u16 As[128 * 32], Bs[128 * 32];
  const int h = blockIdx.z;
  const int y = blockIdx.y;
  const int br = (y == 0) ? 0 : (y == 1) ? 1 : (y < 4) ? 2 : 3;
  const int mt = (y <= 1) ? 0 : (y < 4) ? (y - 2) : (y - 4);
  const int Ci = 64 << br;
  const int coff = (br == 0) ? 0 : (br == 1) ? 64 : (br == 2) ? 192 : 448;
  const int wqo = (br == 0) ? 0 : (br == 1) ? 8192 : (br == 2) ? 24576 : 90112;
  const int n0 = blockIdx.x * 128;
  const u16* A = WqB + (size_t)h * 352256 + wqo + (size_t)mt * 128 * Ci;
  const u16* B = embA + (size_t)(b0 * 224 + n0) * 960 + coff;
  f32x4 acc[4][4] = {};
  mfma_core(A, Ci, B, 960, Ci, acc, As, Bs);
  const int tid = threadIdx.x, l = tid & 63, w = tid >> 6, wm = w >> 1, wn = w & 1;
  u16* C = Qt + (size_t)h * 1024 * NB;
#pragma unroll
  for (int i = 0; i < 4; ++i) {
    const int lr0 = mt * 128 + wm * 64 + i * 16 + (l >> 4) * 4;
#pragma unroll
    for (int j = 0; j < 4; ++j) {
      const int n = n0 + wn * 64 + j * 16 + (l & 15);
#pragma unroll
      for (int r = 0; r < 4; ++r)
        if (lr0 + r < Ci)
          C[(size_t)(coff + lr0 + r) * NB + n] = f2bf(acc[i][j][r]);
    }
  }
}

// ---------------------------------------------------------------------------
// Fused attention, two passes over (z = lb*4+h, ct = c-tile of 128 rows).
// FULL=false: accumulate per-(z,branch) sum/sumsq of S (S discarded).
// FULL=true : S chunk -> p = exp((S*scale - mean)*rs) -> PV accumulate in regs
//             -> normalize by rowsum -> ctxh[z][n 224][c 1024] (bf16).
// Q tile LDS-resident; K staged per 128-o chunk; V read direct from global.
// Grid (Z, 8): flat = z + Z*ct -> all 8 ct-blocks of a z share an XCD.
// ---------------------------------------------------------------------------
template<bool FULL>
__global__ __launch_bounds__(256, 1) void k_attn(
    const u16* __restrict__ Qt, const u16* __restrict__ Kt,
    const u16* __restrict__ V, float* __restrict__ stats,
    u16* __restrict__ ctxh, int NB)
{
  __shared__ u16 Qs[128 * 232];
  __shared__ u16 Ks[128 * 232];
  __shared__ u16 Ps[128 * 136];
  __shared__ float rsumL[128];
  __shared__ float sb[8];

  const int z = blockIdx.x, ct = blockIdx.y;
  const int lb = z >> 2, h = z & 3;
  const int c0 = ct * 128;
  const int tid = threadIdx.x, l = tid & 63;
  const int w = tid >> 6, wm = w >> 1, wn = w & 1;
  const float scale = 0.03227486121839514f;   // 1/sqrt(960)

  const u16* Qz = Qt + (size_t)h * 1024 * NB + (size_t)lb * 224;
  const u16* Kz = Kt + (size_t)h * 1024 * NB + (size_t)lb * 224;
  const u16* Vz = V + (size_t)z * 256 * 1024;

  if (!FULL && tid < 8) sb[tid] = 0.f;

  // stage Q tile [128 c-rows][224 k] -> Qs[128][232]
  for (int u = tid; u < 128 * 28; u += 256) {
    const int r = u / 28, um = u - r * 28;
    *(uint4*)(Qs + r * 232 + um * 8) =
        *(const uint4*)(Qz + (size_t)(c0 + r) * NB + um * 8);
  }

  float mb[4], rb[4];
  if (FULL) {
#pragma unroll
    for (int i = 0; i < 4; ++i) {
      const int row = c0 + wm * 64 + i * 16;
      const int br = (row < 64) ? 0 : (row < 192) ? 1 : (row < 448) ? 2 : 3;
      const float cnt = (float)(64 << br) * 960.f;
      const float s0 = stats[z * 8 + br * 2], s1 = stats[z * 8 + br * 2 + 1];
      const float mean = s0 / cnt;
      const float var = s1 / cnt - mean * mean;
      mb[i] = mean;
      rb[i] = rsqrtf(var + 1e-5f);
    }
  }

  f32x4 cacc[7][4] = {};       // FULL: ctx tile [224 n][128 c] across chunks
  float rt[4][4] = {};         // FULL: per-thread rowsum partials
  float ss[4] = {}, sq[4] = {};// STAT: per-i sums

  for (int oc = 0; oc < 8; ++oc) {
    const int o0 = oc * 128;
    __syncthreads();           // Qs ready / prev S-phase done with Ks
    for (int u = tid; u < 128 * 28; u += 256) {
      const int r = u / 28, um = u - r * 28;
      *(uint4*)(Ks + r * 232 + um * 8) =
          *(const uint4*)(Kz + (size_t)(o0 + r) * NB + um * 8);
    }
    __syncthreads();

    // S chunk: [128 c][128 o], K = 224 (7 k-steps)
    f32x4 sacc[4][4] = {};
#pragma unroll
    for (int ks = 0; ks < 7; ++ks) {
      bf16x8 av[4], bv[4];
#pragma unroll
      for (int i = 0; i < 4; ++i) {
        av[i] = *(const bf16x8*)(Qs + (size_t)(wm * 64 + i * 16 + (l & 15)) * 232 + ks * 32 + (l >> 4) * 8);
        bv[i] = *(const bf16x8*)(Ks + (size_t)(wn * 64 + i * 16 + (l & 15)) * 232 + ks * 32 + (l >> 4) * 8);
      }
#pragma unroll
      for (int i = 0; i < 4; ++i)
#pragma unroll
        for (int j = 0; j < 4; ++j)
          sacc[i][j] = __builtin_amdgcn_mfma_f32_16x16x32_bf16(av[i], bv[j], sacc[i][j], 0, 0, 0);
    }

    if (!FULL) {
#pragma unroll
      for (int i = 0; i < 4; ++i) {
        float sv = 0.f, qv = 0.f;
#pragma unroll
        for (int j = 0; j < 4; ++j)
#pragma unroll
          for (int r = 0; r < 4; ++r) {
            const float v = sacc[i][j][r] * scale;
            sv += v; qv += v * v;
          }
        ss[i] += sv; sq[i] += qv;
      }
    } else {
#pragma unroll
      for (int i = 0; i < 4; ++i)
#pragma unroll
        for (int j = 0; j < 4; ++j) {
          const int colg = o0 + wn * 64 + j * 16 + (l & 15);
          const float keep = (colg < 960) ? 1.f : 0.f;
#pragma unroll
          for (int r = 0; r < 4; ++r) {
            const float v = sacc[i][j][r] * scale;
            const float p = __expf((v - mb[i]) * rb[i]) * keep;
            rt[i][r] += p;
            Ps[(size_t)(wm * 64 + i * 16 + (l >> 4) * 4 + r) * 136 + wn * 64 + j * 16 + (l & 15)] = f2bf(p);
          }
        }
      __syncthreads();         // P tile ready
      // PV: ctx[n, c] += V[n, o-chunk] . P[c, o-chunk]^T  (4 k-steps)
#pragma unroll
      for (int ks = 0; ks < 4; ++ks) {
        bf16x8 pv[4];
#pragma unroll
        for (int j = 0; j < 4; ++j)
          pv[j] = *(const bf16x8*)(Ps + (size_t)(wn * 64 + j * 16 + (l & 15)) * 136 + ks * 32 + (l >> 4) * 8);
#pragma unroll
        for (int i2 = 0; i2 < 7; ++i2) {
          const bf16x8 av = *(const bf16x8*)(Vz + (size_t)(wm * 112 + i2 * 16 + (l & 15)) * 1024 + o0 + ks * 32 + (l >> 4) * 8);
#pragma unroll
          for (int j = 0; j < 4; ++j)
            cacc[i2][j] = __builtin_amdgcn_mfma_f32_16x16x32_bf16(av, pv[j], cacc[i2][j], 0, 0, 0);
        }
      }
    }
  }

  if (!FULL) {
    __syncthreads();
#pragma unroll
    for (int i = 0; i < 4; ++i) {
      const int row16 = c0 + wm * 64 + i * 16;
      if (row16 < 960) {       // exclude never-written Qt pad rows
        const int br = (row16 < 64) ? 0 : (row16 < 192) ? 1 : (row16 < 448) ? 2 : 3;
        atomicAdd(&sb[br * 2], ss[i]);
        atomicAdd(&sb[br * 2 + 1], sq[i]);
      }
    }
    __syncthreads();
    if (tid < 8) atomicAdd(stats + (size_t)z * 8 + tid, sb[tid]);
  } else {
    // rowsum: reduce rt over the 16 lanes sharing each row, then across wn
    if (tid < 128) rsumL[tid] = 0.f;
    __syncthreads();
#pragma unroll
    for (int i = 0; i < 4; ++i)
#pragma unroll
      for (int r = 0; r < 4; ++r) {
        float v = rt[i][r];
        v += __shfl_xor(v, 1);
        v += __shfl_xor(v, 2);
        v += __shfl_xor(v, 4);
        v += __shfl_xor(v, 8);
        if ((l & 15) == 0)
          atomicAdd(&rsumL[wm * 64 + i * 16 + (l >> 4) * 4 + r], v);
      }
    __syncthreads();
    if (tid < 128) rsumL[tid] = 1.f / rsumL[tid];
    __syncthreads();
    // normalized ctx -> ctxh, staged through Ps in two 112-row passes
    u16* dst = ctxh + (size_t)z * 229376 + c0;
#pragma unroll
    for (int pass = 0; pass < 2; ++pass) {
      if (wm == pass) {
#pragma unroll
        for (int i2 = 0; i2 < 7; ++i2)
#pragma unroll
          for (int j = 0; j < 4; ++j) {
            const int col = wn * 64 + j * 16 + (l & 15);
            const float inv = rsumL[col];
#pragma unroll
            for (int r = 0; r < 4; ++r)
              Ps[(size_t)(i2 * 16 + (l >> 4) * 4 + r) * 136 + col] = f2bf(cacc[i2][j][r] * inv);
          }
      }
      __syncthreads();
      for (int u = tid; u < 112 * 16; u += 256) {
        const int rr = u / 16, um = u - rr * 16;
        *(uint4*)(dst + (size_t)(pass * 112 + rr) * 1024 + um * 8) =
            *(const uint4*)(Ps + rr * 136 + um * 8);
      }
      __syncthreads();
    }
  }
}

// ctx[lb][n][c] = bf16( 0.25 * sum_h ctxh[lb*4+h][n][c] )
__global__ __launch_bounds__(256) void k_ctxred(const u16* __restrict__ ctxh,
    u16* __restrict__ ctx, int Bc)
{
  const long long i8 = ((long long)blockIdx.x * 256 + threadIdx.x) * 8;
  if (i8 >= (long long)Bc * 229376) return;
  const int lb = (int)(i8 / 229376);
  const int off = (int)(i8 - (long long)lb * 229376);
  const u16* p = ctxh + (size_t)lb * 4 * 229376 + off;
  float s[8] = {};
#pragma unroll
  for (int h = 0; h < 4; ++h) {
    bf16x8 v = *(const bf16x8*)(p + (size_t)h * 229376);
#pragma unroll
    for (int i = 0; i < 8; ++i) s[i] += bf2f((u16)v[i]);
  }
  bf16x8 o;
#pragma unroll
  for (int i = 0; i < 8; ++i) o[i] = (short)f2bf(s[i] * 0.25f);
  *(bf16x8*)(ctx + (size_t)lb * 262144 + off) = o;
}

// O_br[b][n][c'] = ctx[b][n, coff:coff+Ci] . Wo_br^T   (f32 to d_out)
__global__ __launch_bounds__(256) void k_o(const u16* __restrict__ ctx,
    const u16* __restrict__ WoB, float* __restrict__ out, int b0)
{
  __shared__ u16 As[128 * 32], Bs[128 * 32];
  const int lb = blockIdx.z;
  const int x = blockIdx.x;
  const int br = (x == 0) ? 0 : (x == 1) ? 1 : (x < 4) ? 2 : 3;
  const int nt = (x <= 1) ? 0 : (x < 4) ? (x - 2) : (x - 4);
  const int Ci = 64 << br;
  const int coff = (br == 0) ? 0 : (br == 1) ? 64 : (br == 2) ? 192 : 448;
  const int woo = (br == 0) ? 0 : (br == 1) ? 8192 : (br == 2) ? 24576 : 90112;
  const long long ob = (br == 0) ? 0LL : (br == 1) ? 401408LL : (br == 2) ? 1204224LL : 2809856LL;
  const int m0 = blockIdx.y * 128;
  const u16* A = ctx + (size_t)lb * 262144 + (size_t)m0 * 1024 + coff;
  const u16* B = WoB + woo + (size_t)nt * 128 * Ci;
  f32x4 acc[4][4] = {};
  mfma_core(A, 1024, B, Ci, Ci, acc, As, Bs);
  const int tid = threadIdx.x, l = tid & 63, w = tid >> 6, wm = w >> 1, wn = w & 1;
  float* O = out + ob;
  const int gb = b0 + lb;
#pragma unroll
  for (int i = 0; i < 4; ++i) {
    const int row0 = m0 + wm * 64 + i * 16 + (l >> 4) * 4;
#pragma unroll
    for (int j = 0; j < 4; ++j) {
      const int cg = nt * 128 + wn * 64 + j * 16 + (l & 15);
#pragma unroll
      for (int r = 0; r < 4; ++r) {
        const int row = row0 + r;
        if (row < 196 && cg < Ci)
          O[((size_t)gb * 196 + row) * Ci + cg] = acc[i][j][r];
      }
    }
  }
}

// ---------------------------------------------------------------------------
extern "C" void kernel_launch(void* const* d_in, const int* in_sizes, int n_in,
                              void* d_out, int out_size, void* d_ws, size_t ws_size,
                              hipStream_t stream)
{
  const float* eall = (const float*)d_in[4];
  const float* Wq1 = (const float*)d_in[5];
  const float* Wq2 = (const float*)d_in[6];
  const float* Wq3 = (const float*)d_in[7];
  const float* Wq4 = (const float*)d_in[8];
  const float* Wk  = (const float*)d_in[9];
  const float* Wv  = (const float*)d_in[10];
  const float* Wo1 = (const float*)d_in[11];
  const float* Wo2 = (const float*)d_in[12];
  const float* Wo3 = (const float*)d_in[13];
  const float* Wo4 = (const float*)d_in[14];
  float* out = (float*)d_out;

  char* p = (char*)d_ws;
  auto alloc = [&](size_t bytes) -> void* {
    void* r = p; p += (bytes + 255) & ~(size_t)255; return r;
  };
  u16* embA = (u16*)alloc((size_t)7168 * 960 * 2);
  u16* WkB  = (u16*)alloc((size_t)4 * 1024 * 960 * 2);
  u16* WvB  = (u16*)alloc((size_t)4 * 1024 * 960 * 2);
  u16* WqB  = (u16*)alloc((size_t)4 * 352256 * 2);
  u16* WoB  = (u16*)alloc((size_t)352256 * 2);
  const size_t persist = (size_t)(p - (char*)d_ws);
  // per-batch: Kt + Qt (2 x 4*1024*224*2) + V (4*256*1024*2)
  //          + ctxh (4*224*1024*2) + ctx (256*1024*2) + stats (128B)
  const size_t perBatch = (size_t)1835008 * 2 + 2097152 + 1835008 + 524288 + 128 + 512;
  int Bc = 8;
  if      (persist + 32 * perBatch <= ws_size) Bc = 32;
  else if (persist + 16 * perBatch <= ws_size) Bc = 16;
  const int NB = Bc * 224;

  u16* Kt  = (u16*)alloc((size_t)4 * 1024 * NB * 2);
  u16* Qt  = (u16*)alloc((size_t)4 * 1024 * NB * 2);
  u16* V   = (u16*)alloc((size_t)Bc * 4 * 256 * 1024 * 2);
  u16* ctxh = (u16*)alloc((size_t)Bc * 4 * 229376 * 2);
  u16* ctx = (u16*)alloc((size_t)Bc * 262144 * 2);
  float* stats = (float*)alloc((size_t)Bc * 32 * 4);

  const dim3 blk(256);
  auto cvt = [&](const float* src, u16* dst, int srcR, int dstR, int C,
                 long long stride, long long off, int g) {
    long long total = (long long)g * dstR * C;
    int gridc = (int)((total + 255) / 256);
    k_padcvt<<<dim3(gridc), blk, 0, stream>>>(src, dst, srcR, dstR, C, stride, off, total);
  };
  cvt(eall, embA, 196, 224, 960, (long long)224 * 960, 0, 32);
  cvt(Wk, WkB, 960, 1024, 960, (long long)1024 * 960, 0, 4);
  cvt(Wv, WvB, 960, 1024, 960, (long long)1024 * 960, 0, 4);
  cvt(Wq1, WqB, 64, 128, 64,   352256, 0,     4);
  cvt(Wq2, WqB, 128, 128, 128, 352256, 8192,  4);
  cvt(Wq3, WqB, 256, 256, 256, 352256, 24576, 4);
  cvt(Wq4, WqB, 512, 512, 512, 352256, 90112, 4);
  cvt(Wo1, WoB, 64, 128, 64,   0, 0,     1);
  cvt(Wo2, WoB, 128, 128, 128, 0, 8192,  1);
  cvt(Wo3, WoB, 256, 256, 256, 0, 24576, 1);
  cvt(Wo4, WoB, 512, 512, 512, 0, 90112, 1);

  const int NT = NB / 128;
  for (int b0 = 0; b0 < 32; b0 += Bc) {
    hipMemsetAsync(stats, 0, (size_t)Bc * 32 * 4, stream);
    k_kt<<<dim3(NT, 8, 4), blk, 0, stream>>>(embA, WkB, Kt, b0, NB);
    k_v <<<dim3(8, NT, 4), blk, 0, stream>>>(embA, WvB, V, b0, NB);
    k_q <<<dim3(NT, 8, 4), blk, 0, stream>>>(embA, WqB, Qt, b0, NB);
    k_attn<false><<<dim3(Bc * 4, 8), blk, 0, stream>>>(Qt, Kt, V, stats, ctxh, NB);
    k_attn<true> <<<dim3(Bc * 4, 8), blk, 0, stream>>>(Qt, Kt, V, stats, ctxh, NB);
    k_ctxred<<<dim3((Bc * 229376 / 8 + 255) / 256), blk, 0, stream>>>(ctxh, ctx, Bc);
    k_o <<<dim3(8, 2, Bc), blk, 0, stream>>>(ctx, WoB, out, b0);
  }
}

// Round 5
// 852.219 us; speedup vs baseline: 1.2933x; 1.2933x over previous
//
#include <hip/hip_runtime.h>
#include <math.h>

typedef __attribute__((ext_vector_type(8))) short bf16x8;   // 8 bf16 in 4 VGPRs
typedef __attribute__((ext_vector_type(4))) float f32x4;
typedef unsigned short u16;

__device__ __forceinline__ u16 f2bf(float f) {
  unsigned u = __float_as_uint(f);
  return (u16)((u + 0x7FFFu + ((u >> 16) & 1u)) >> 16);   // RNE
}
__device__ __forceinline__ float bf2f(u16 h) {
  return __uint_as_float(((unsigned)h) << 16);
}

__device__ __forceinline__ void gload16(const u16* g, void* lds) {
  __builtin_amdgcn_global_load_lds(
      (const __attribute__((address_space(1))) unsigned int*)g,
      (__attribute__((address_space(3))) unsigned int*)lds, 16, 0, 0);
}

// ---------------------------------------------------------------------------
// MFMA core (proven in R2): 128x128 tile, BK=32, 256 threads (4 waves = 2x2
// quadrants of 4x4 16x16x32 fragments). K mult of 32; padded buffers.
// ---------------------------------------------------------------------------
__device__ __forceinline__ void mfma_core(
    const u16* __restrict__ A, int lda,
    const u16* __restrict__ B, int ldb,
    int K, f32x4 (&acc)[4][4], u16* As, u16* Bs)
{
  const int tid = threadIdx.x;
  const int l = tid & 63, w = tid >> 6;
  const int srow = w * 16 + (l >> 2);
  const int kel  = (l & 3) * 8;
  char* AsB = (char*)As + w * 1024;
  char* BsB = (char*)Bs + w * 1024;
  const u16* Ap  = A + (size_t)srow * lda + kel;
  const u16* Ap2 = A + (size_t)(srow + 64) * lda + kel;
  const u16* Bp  = B + (size_t)srow * ldb + kel;
  const u16* Bp2 = B + (size_t)(srow + 64) * ldb + kel;
  const int wm = w >> 1, wn = w & 1;
  const int aoff = (wm * 64 + (l & 15)) * 32 + (l >> 4) * 8;
  const int boff = (wn * 64 + (l & 15)) * 32 + (l >> 4) * 8;
  for (int kb = 0; kb < K; kb += 32) {
    __syncthreads();
    gload16(Ap + kb,  AsB);
    gload16(Ap2 + kb, AsB + 4096);
    gload16(Bp + kb,  BsB);
    gload16(Bp2 + kb, BsB + 4096);
    __syncthreads();
    bf16x8 av[4], bv[4];
#pragma unroll
    for (int i = 0; i < 4; ++i) {
      av[i] = *(const bf16x8*)(As + aoff + i * 16 * 32);
      bv[i] = *(const bf16x8*)(Bs + boff + i * 16 * 32);
    }
#pragma unroll
    for (int i = 0; i < 4; ++i)
#pragma unroll
      for (int j = 0; j < 4; ++j)
        acc[i][j] = __builtin_amdgcn_mfma_f32_16x16x32_bf16(av[i], bv[j], acc[i][j], 0, 0, 0);
  }
}

// ---------------------------------------------------------------------------
// One-shot pad/convert of all inputs (11 segments, hardcoded boundaries).
// ---------------------------------------------------------------------------
__global__ __launch_bounds__(256) void k_cvt(
    const float* __restrict__ eall,
    const float* __restrict__ Wq1, const float* __restrict__ Wq2,
    const float* __restrict__ Wq3, const float* __restrict__ Wq4,
    const float* __restrict__ Wk, const float* __restrict__ Wv,
    const float* __restrict__ Wo1, const float* __restrict__ Wo2,
    const float* __restrict__ Wo3, const float* __restrict__ Wo4,
    u16* __restrict__ embA, u16* __restrict__ WkB, u16* __restrict__ WvB,
    u16* __restrict__ WqB, u16* __restrict__ WoB)
{
  long long idx = (long long)blockIdx.x * 256 + threadIdx.x;
  const float* src; u16* dst; int srcR, dstR, C; long long stride, off, loc;
  if (idx < 6881280LL)       { loc = idx;               src=eall; dst=embA; srcR=196; dstR=224;  C=960; stride=215040; off=0; }
  else if (idx < 10813440LL) { loc = idx - 6881280LL;   src=Wk;   dst=WkB;  srcR=960; dstR=1024; C=960; stride=983040; off=0; }
  else if (idx < 14745600LL) { loc = idx - 10813440LL;  src=Wv;   dst=WvB;  srcR=960; dstR=1024; C=960; stride=983040; off=0; }
  else if (idx < 14778368LL) { loc = idx - 14745600LL;  src=Wq1;  dst=WqB;  srcR=64;  dstR=128;  C=64;  stride=352256; off=0; }
  else if (idx < 14843904LL) { loc = idx - 14778368LL;  src=Wq2;  dst=WqB;  srcR=128; dstR=128;  C=128; stride=352256; off=8192; }
  else if (idx < 15106048LL) { loc = idx - 14843904LL;  src=Wq3;  dst=WqB;  srcR=256; dstR=256;  C=256; stride=352256; off=24576; }
  else if (idx < 16154624LL) { loc = idx - 15106048LL;  src=Wq4;  dst=WqB;  srcR=512; dstR=512;  C=512; stride=352256; off=90112; }
  else if (idx < 16162816LL) { loc = idx - 16154624LL;  src=Wo1;  dst=WoB;  srcR=64;  dstR=128;  C=64;  stride=0; off=0; }
  else if (idx < 16179200LL) { loc = idx - 16162816LL;  src=Wo2;  dst=WoB;  srcR=128; dstR=128;  C=128; stride=0; off=8192; }
  else if (idx < 16244736LL) { loc = idx - 16179200LL;  src=Wo3;  dst=WoB;  srcR=256; dstR=256;  C=256; stride=0; off=24576; }
  else if (idx < 16506880LL) { loc = idx - 16244736LL;  src=Wo4;  dst=WoB;  srcR=512; dstR=512;  C=512; stride=0; off=90112; }
  else return;
  const long long per = (long long)dstR * C;
  const int g = (int)(loc / per);
  const int r2 = (int)(loc % per);
  const int rr = r2 / C, c = r2 - rr * C;
  const float v = (rr < srcR) ? src[((long long)g * srcR + rr) * C + c] : 0.f;
  dst[g * stride + off + (long long)rr * C + c] = f2bf(v);
}

// Kt[h][o(1024)][NB] = Wk[h] x embA^T
__global__ __launch_bounds__(256) void k_kt(const u16* __restrict__ embA,
    const u16* __restrict__ WkB, u16* __restrict__ Kt, int b0, int NB)
{
  __shared__ u16 As[128 * 32], Bs[128 * 32];
  const int h = blockIdx.z;
  const int m0 = blockIdx.y * 128, n0 = blockIdx.x * 128;
  const u16* A = WkB + (size_t)h * 1024 * 960 + (size_t)m0 * 960;
  const u16* B = embA + (size_t)(b0 * 224 + n0) * 960;
  f32x4 acc[4][4] = {};
  mfma_core(A, 960, B, 960, 960, acc, As, Bs);
  const int tid = threadIdx.x, l = tid & 63, w = tid >> 6, wm = w >> 1, wn = w & 1;
  u16* C = Kt + (size_t)h * 1024 * NB;
#pragma unroll
  for (int i = 0; i < 4; ++i) {
    const int gm0 = m0 + wm * 64 + i * 16 + (l >> 4) * 4;
#pragma unroll
    for (int j = 0; j < 4; ++j) {
      const int n = n0 + wn * 64 + j * 16 + (l & 15);
#pragma unroll
      for (int r = 0; r < 4; ++r)
        C[(size_t)(gm0 + r) * NB + n] = f2bf(acc[i][j][r]);
    }
  }
}

// V[lb][h][n(256 pad)][o(1024)] = embA x Wv[h]^T
__global__ __launch_bounds__(256) void k_v(const u16* __restrict__ embA,
    const u16* __restrict__ WvB, u16* __restrict__ V, int b0, int NB)
{
  __shared__ u16 As[128 * 32], Bs[128 * 32];
  const int h = blockIdx.z;
  const int m0 = blockIdx.y * 128, n0 = blockIdx.x * 128;
  const u16* A = embA + (size_t)(b0 * 224 + m0) * 960;
  const u16* B = WvB + (size_t)h * 1024 * 960 + (size_t)n0 * 960;
  f32x4 acc[4][4] = {};
  mfma_core(A, 960, B, 960, 960, acc, As, Bs);
  const int tid = threadIdx.x, l = tid & 63, w = tid >> 6, wm = w >> 1, wn = w & 1;
#pragma unroll
  for (int i = 0; i < 4; ++i) {
    const int t0 = m0 + wm * 64 + i * 16 + (l >> 4) * 4;
#pragma unroll
    for (int r = 0; r < 4; ++r) {
      const int t = t0 + r;
      const int lb = t / 224, n = t - lb * 224;
      u16* C = V + ((size_t)(lb * 4 + h) * 256 + n) * 1024;
#pragma unroll
      for (int j = 0; j < 4; ++j) {
        const int col = n0 + wn * 64 + j * 16 + (l & 15);
        C[col] = f2bf(acc[i][j][r]);
      }
    }
  }
}

// Qt[h][ccat(1024)][NB] = Wq_br[h] x emb_br^T  (branch slices read from embA)
__global__ __launch_bounds__(256) void k_q(const u16* __restrict__ embA,
    const u16* __restrict__ WqB, u16* __restrict__ Qt, int b0, int NB)
{
  __shared__ u16 As[128 * 32], Bs[128 * 32];
  const int h = blockIdx.z;
  const int y = blockIdx.y;
  const int br = (y == 0) ? 0 : (y == 1) ? 1 : (y < 4) ? 2 : 3;
  const int mt = (y <= 1) ? 0 : (y < 4) ? (y - 2) : (y - 4);
  const int Ci = 64 << br;
  const int coff = (br == 0) ? 0 : (br == 1) ? 64 : (br == 2) ? 192 : 448;
  const int wqo = (br == 0) ? 0 : (br == 1) ? 8192 : (br == 2) ? 24576 : 90112;
  const int n0 = blockIdx.x * 128;
  const u16* A = WqB + (size_t)h * 352256 + wqo + (size_t)mt * 128 * Ci;
  const u16* B = embA + (size_t)(b0 * 224 + n0) * 960 + coff;
  f32x4 acc[4][4] = {};
  mfma_core(A, Ci, B, 960, Ci, acc, As, Bs);
  const int tid = threadIdx.x, l = tid & 63, w = tid >> 6, wm = w >> 1, wn = w & 1;
  u16* C = Qt + (size_t)h * 1024 * NB;
#pragma unroll
  for (int i = 0; i < 4; ++i) {
    const int lr0 = mt * 128 + wm * 64 + i * 16 + (l >> 4) * 4;
#pragma unroll
    for (int j = 0; j < 4; ++j) {
      const int n = n0 + wn * 64 + j * 16 + (l & 15);
#pragma unroll
      for (int r = 0; r < 4; ++r)
        if (lr0 + r < Ci)
          C[(size_t)(coff + lr0 + r) * NB + n] = f2bf(acc[i][j][r]);
    }
  }
}

// S[z][c(1024)][o(1024)] = (Qt . Kt^T)/sqrt(960), + per-(z,branch) sum/sumsq
__global__ __launch_bounds__(256) void k_s(const u16* __restrict__ Qt,
    const u16* __restrict__ Kt, u16* __restrict__ S, float* __restrict__ stats,
    int NB)
{
  __shared__ u16 As[128 * 32], Bs[128 * 32];
  __shared__ float sb[8];
  const int tid = threadIdx.x;
  if (tid < 8) sb[tid] = 0.f;
  const int z = blockIdx.z;           // lb*4 + h
  const int lb = z >> 2, h = z & 3;
  const int m0 = blockIdx.y * 128, n0 = blockIdx.x * 128;
  const u16* A = Qt + (size_t)h * 1024 * NB + (size_t)m0 * NB + lb * 224;
  const u16* B = Kt + (size_t)h * 1024 * NB + (size_t)n0 * NB + lb * 224;
  f32x4 acc[4][4] = {};
  mfma_core(A, NB, B, NB, 224, acc, As, Bs);
  const int l = tid & 63, w = tid >> 6, wm = w >> 1, wn = w & 1;
  u16* C = S + (size_t)z * 1024 * 1024;
  const float scale = 0.03227486121839514f;   // 1/sqrt(960)
#pragma unroll
  for (int i = 0; i < 4; ++i) {
    const int gm0 = m0 + wm * 64 + i * 16 + (l >> 4) * 4;
    const int br = (gm0 < 64) ? 0 : (gm0 < 192) ? 1 : (gm0 < 448) ? 2 : 3;
    float sv = 0.f, qv = 0.f;
#pragma unroll
    for (int j = 0; j < 4; ++j) {
      const int n = n0 + wn * 64 + j * 16 + (l & 15);
#pragma unroll
      for (int r = 0; r < 4; ++r) {
        const float v = acc[i][j][r] * scale;
        C[(size_t)(gm0 + r) * 1024 + n] = f2bf(v);
        sv += v; qv += v * v;
      }
    }
    if (gm0 < 960) {                 // exclude never-written Qt pad rows
      atomicAdd(&sb[br * 2], sv);
      atomicAdd(&sb[br * 2 + 1], qv);
    }
  }
  __syncthreads();
  if (tid < 8) atomicAdd(stats + (size_t)z * 8 + tid, sb[tid]);
}

// ---------------------------------------------------------------------------
// Fused exp+PV: ctxh[z][n(224)][ct*64..+64] = (exp-normalized P) x V.
// Block = (ct 0..14, z). 64 c-rows/block (one branch -> uniform mean/rs).
// Reads raw S once; rowsum-normalizes at the end (no row-max needed:
// InstanceNorm bounds the exp argument).
// ---------------------------------------------------------------------------
__global__ __launch_bounds__(256) void k_pvf(
    const u16* __restrict__ S, const float* __restrict__ stats,
    const u16* __restrict__ V, u16* __restrict__ ctxh)
{
  __shared__ u16 Vs[224 * 40];
  __shared__ u16 Ps[64 * 40];
  __shared__ float rsumL[64];

  const int ct = blockIdx.x;        // 0..14 (c rows ct*64..+64, all real)
  const int z  = blockIdx.y;
  const int tid = threadIdx.x, l = tid & 63;
  const int w = tid >> 6, wm = w >> 1, wn = w & 1;

  const u16* Sz = S + (size_t)z * 1024 * 1024 + (size_t)ct * 64 * 1024;
  const u16* Vz = V + (size_t)z * 256 * 1024;

  const int br = (ct == 0) ? 0 : (ct < 3) ? 1 : (ct < 7) ? 2 : 3;
  const float cnt = (float)(64 << br) * 960.f;
  const float s0 = stats[z * 8 + br * 2], s1 = stats[z * 8 + br * 2 + 1];
  const float mean = s0 / cnt;
  const float var = s1 / cnt - mean * mean;
  const float rs = rsqrtf(var + 1e-5f);

  if (tid < 64) rsumL[tid] = 0.f;

  const int pr = tid >> 2;          // P row 0..63
  const int pq = tid & 3;           // col quarter
  float rowsum = 0.f;

  f32x4 cacc[7][2] = {};

  for (int kb = 0; kb < 960; kb += 32) {
    __syncthreads();                // Vs/Ps free (prev MFMA done)
    // stage V [224][32] -> Vs[224][40]
#pragma unroll
    for (int it = 0; it < 4; ++it) {
      const int idx = it * 256 + tid;
      if (idx < 896) {
        const int vr = idx >> 2, vc = idx & 3;
        *(bf16x8*)(Vs + vr * 40 + vc * 8) =
            *(const bf16x8*)(Vz + (size_t)vr * 1024 + kb + vc * 8);
      }
    }
    // stage P = exp((s - mean)*rs) [64][32] -> Ps[64][40]
    {
      const bf16x8 sv = *(const bf16x8*)(Sz + (size_t)pr * 1024 + kb + pq * 8);
      bf16x8 pv;
#pragma unroll
      for (int i = 0; i < 8; ++i) {
        const float p = __expf((bf2f((u16)sv[i]) - mean) * rs);
        rowsum += p;
        pv[i] = (short)f2bf(p);
      }
      *(bf16x8*)(Ps + pr * 40 + pq * 8) = pv;
    }
    __syncthreads();
    // MFMA: [224 n] x [64 c], K=32
    bf16x8 bv[2];
#pragma unroll
    for (int j = 0; j < 2; ++j)
      bv[j] = *(const bf16x8*)(Ps + (wn * 32 + j * 16 + (l & 15)) * 40 + (l >> 4) * 8);
#pragma unroll
    for (int i2 = 0; i2 < 7; ++i2) {
      const bf16x8 av = *(const bf16x8*)(Vs + (wm * 112 + i2 * 16 + (l & 15)) * 40 + (l >> 4) * 8);
#pragma unroll
      for (int j = 0; j < 2; ++j)
        cacc[i2][j] = __builtin_amdgcn_mfma_f32_16x16x32_bf16(av, bv[j], cacc[i2][j], 0, 0, 0);
    }
  }
  __syncthreads();
  atomicAdd(&rsumL[pr], rowsum);
  __syncthreads();
  float inv[2];
#pragma unroll
  for (int j = 0; j < 2; ++j)
    inv[j] = 1.f / rsumL[wn * 32 + j * 16 + (l & 15)];

  // normalized bf16 ctx -> ctxh, staged via Cs (alias Vs), 2 passes x 112 rows
  u16* Cs = Vs;                      // needs 112*68 = 7616 <= 8960
  u16* dst = ctxh + (size_t)z * 229376 + ct * 64;
#pragma unroll
  for (int pass = 0; pass < 2; ++pass) {
    if (wm == pass) {
#pragma unroll
      for (int i2 = 0; i2 < 7; ++i2)
#pragma unroll
        for (int j = 0; j < 2; ++j) {
          const int col = wn * 32 + j * 16 + (l & 15);
#pragma unroll
          for (int rr = 0; rr < 4; ++rr)
            Cs[(i2 * 16 + (l >> 4) * 4 + rr) * 68 + col] = f2bf(cacc[i2][j][rr] * inv[j]);
        }
    }
    __syncthreads();
#pragma unroll
    for (int it = 0; it < 4; ++it) {
      const int idx = it * 256 + tid;
      if (idx < 896) {
        const int row = idx >> 3, c8 = idx & 7;
        *(uint4*)(dst + (size_t)(pass * 112 + row) * 1024 + c8 * 8) =
            *(const uint4*)(Cs + row * 68 + c8 * 8);
      }
    }
    __syncthreads();
  }
}

// ctx[lb][n][c] = bf16( 0.25 * sum_h ctxh[lb*4+h][n][c] )
__global__ __launch_bounds__(256) void k_ctxred(const u16* __restrict__ ctxh,
    u16* __restrict__ ctx, int Bc)
{
  const long long i8 = ((long long)blockIdx.x * 256 + threadIdx.x) * 8;
  if (i8 >= (long long)Bc * 229376) return;
  const int lb = (int)(i8 / 229376);
  const int off = (int)(i8 - (long long)lb * 229376);
  const u16* p = ctxh + (size_t)lb * 4 * 229376 + off;
  float s[8] = {};
#pragma unroll
  for (int h = 0; h < 4; ++h) {
    bf16x8 v = *(const bf16x8*)(p + (size_t)h * 229376);
#pragma unroll
    for (int i = 0; i < 8; ++i) s[i] += bf2f((u16)v[i]);
  }
  bf16x8 o;
#pragma unroll
  for (int i = 0; i < 8; ++i) o[i] = (short)f2bf(s[i] * 0.25f);
  *(bf16x8*)(ctx + (size_t)lb * 262144 + off) = o;
}

// O_br[b][n][c'] = ctx[b][n, coff:coff+Ci] . Wo_br^T   (f32 to d_out)
__global__ __launch_bounds__(256) void k_o(const u16* __restrict__ ctx,
    const u16* __restrict__ WoB, float* __restrict__ out, int b0)
{
  __shared__ u16 As[128 * 32], Bs[128 * 32];
  const int lb = blockIdx.z;
  const int x = blockIdx.x;
  const int br = (x == 0) ? 0 : (x == 1) ? 1 : (x < 4) ? 2 : 3;
  const int nt = (x <= 1) ? 0 : (x < 4) ? (x - 2) : (x - 4);
  const int Ci = 64 << br;
  const int coff = (br == 0) ? 0 : (br == 1) ? 64 : (br == 2) ? 192 : 448;
  const int woo = (br == 0) ? 0 : (br == 1) ? 8192 : (br == 2) ? 24576 : 90112;
  const long long ob = (br == 0) ? 0LL : (br == 1) ? 401408LL : (br == 2) ? 1204224LL : 2809856LL;
  const int m0 = blockIdx.y * 128;
  const u16* A = ctx + (size_t)lb * 262144 + (size_t)m0 * 1024 + coff;
  const u16* B = WoB + woo + (size_t)nt * 128 * Ci;
  f32x4 acc[4][4] = {};
  mfma_core(A, 1024, B, Ci, Ci, acc, As, Bs);
  const int tid = threadIdx.x, l = tid & 63, w = tid >> 6, wm = w >> 1, wn = w & 1;
  float* O = out + ob;
  const int gb = b0 + lb;
#pragma unroll
  for (int i = 0; i < 4; ++i) {
    const int row0 = m0 + wm * 64 + i * 16 + (l >> 4) * 4;
#pragma unroll
    for (int j = 0; j < 4; ++j) {
      const int cg = nt * 128 + wn * 64 + j * 16 + (l & 15);
#pragma unroll
      for (int r = 0; r < 4; ++r) {
        const int row = row0 + r;
        if (row < 196 && cg < Ci)
          O[((size_t)gb * 196 + row) * Ci + cg] = acc[i][j][r];
      }
    }
  }
}

// ---------------------------------------------------------------------------
extern "C" void kernel_launch(void* const* d_in, const int* in_sizes, int n_in,
                              void* d_out, int out_size, void* d_ws, size_t ws_size,
                              hipStream_t stream)
{
  const float* eall = (const float*)d_in[4];
  const float* Wq1 = (const float*)d_in[5];
  const float* Wq2 = (const float*)d_in[6];
  const float* Wq3 = (const float*)d_in[7];
  const float* Wq4 = (const float*)d_in[8];
  const float* Wk  = (const float*)d_in[9];
  const float* Wv  = (const float*)d_in[10];
  const float* Wo1 = (const float*)d_in[11];
  const float* Wo2 = (const float*)d_in[12];
  const float* Wo3 = (const float*)d_in[13];
  const float* Wo4 = (const float*)d_in[14];
  float* out = (float*)d_out;

  char* p = (char*)d_ws;
  auto alloc = [&](size_t bytes) -> void* {
    void* r = p; p += (bytes + 255) & ~(size_t)255; return r;
  };
  u16* embA = (u16*)alloc((size_t)7168 * 960 * 2);
  u16* WkB  = (u16*)alloc((size_t)4 * 1024 * 960 * 2);
  u16* WvB  = (u16*)alloc((size_t)4 * 1024 * 960 * 2);
  u16* WqB  = (u16*)alloc((size_t)4 * 352256 * 2);
  u16* WoB  = (u16*)alloc((size_t)352256 * 2);
  const size_t persist = (size_t)(p - (char*)d_ws);
  // per-lb: Kt 1.84M + Qt 1.84M + V 2.10M + S 8.39M + ctxh 1.84M + ctx 0.52M
  const size_t perLB = (size_t)1835008 * 2 + 2097152 + 8388608 + 1835008 + 524288 + 128 + 2048;
  int Bc = 8;
  if      (persist + 32 * perLB <= ws_size) Bc = 32;
  else if (persist + 16 * perLB <= ws_size) Bc = 16;
  const int NB = Bc * 224;

  u16* Kt  = (u16*)alloc((size_t)4 * 1024 * NB * 2);
  u16* Qt  = (u16*)alloc((size_t)4 * 1024 * NB * 2);
  u16* V   = (u16*)alloc((size_t)Bc * 4 * 256 * 1024 * 2);
  u16* S   = (u16*)alloc((size_t)Bc * 4 * 1024 * 1024 * 2);
  u16* ctxh = (u16*)alloc((size_t)Bc * 4 * 229376 * 2);
  u16* ctx = (u16*)alloc((size_t)Bc * 262144 * 2);
  float* stats = (float*)alloc((size_t)Bc * 32 * 4);

  const dim3 blk(256);
  k_cvt<<<dim3(64480), blk, 0, stream>>>(eall, Wq1, Wq2, Wq3, Wq4, Wk, Wv,
                                         Wo1, Wo2, Wo3, Wo4,
                                         embA, WkB, WvB, WqB, WoB);

  const int NT = NB / 128;
  for (int b0 = 0; b0 < 32; b0 += Bc) {
    hipMemsetAsync(stats, 0, (size_t)Bc * 32 * 4, stream);
    k_kt<<<dim3(NT, 8, 4), blk, 0, stream>>>(embA, WkB, Kt, b0, NB);
    k_v <<<dim3(8, NT, 4), blk, 0, stream>>>(embA, WvB, V, b0, NB);
    k_q <<<dim3(NT, 8, 4), blk, 0, stream>>>(embA, WqB, Qt, b0, NB);
    k_s <<<dim3(8, 8, Bc * 4), blk, 0, stream>>>(Qt, Kt, S, stats, NB);
    k_pvf<<<dim3(15, Bc * 4), blk, 0, stream>>>(S, stats, V, ctxh);
    k_ctxred<<<dim3((Bc * 229376 / 8 + 255) / 256), blk, 0, stream>>>(ctxh, ctx, Bc);
    k_o <<<dim3(8, 2, Bc), blk, 0, stream>>>(ctx, WoB, out, b0);
  }
}